// Round 1
// baseline (518.070 us; speedup 1.0000x reference)
//
#include <hip/hip_runtime.h>

typedef unsigned long long u64;
typedef __attribute__((ext_vector_type(4)))  int i32x4;
typedef __attribute__((ext_vector_type(16))) int i32x16;

// x [32,256,32,32] f32, w [256,256,3,3] f32; reduction R = 2304 = 36 x 64.
#define NPIX   32768
#define OCH    256
#define NCH    36

// stage 0: zero stats; build the 9 boundary-class chunk masks.
__global__ void bb_init(float* st, u64* masks) {
  int t = threadIdx.x;
  for (int i = t; i < 1024; i += 256) st[i] = 0.f;
  for (int id = t; id < 9 * NCH; id += 256) {
    int cls = id / NCH, ck = id % NCH;
    int ch = cls / 3, cw = cls % 3;
    u64 m = 0;
    for (int b = 0; b < 64; ++b) {
      int r = ck * 64 + b, tap = r % 9, kh = tap / 3, kw = tap % 3;
      bool oob = (ch == 0 && kh == 0) || (ch == 2 && kh == 2) ||
                 (cw == 0 && kw == 0) || (cw == 2 && kw == 2);
      if (!oob) m |= (u64)1 << b;
    }
    masks[id] = m;
  }
}

// stage 1: weight sign bits, TRANSPOSED to WbitsT[layer][chunk][oc] so the
// boundary kernel's per-chunk weight reads coalesce (lanes = consecutive oc).
__global__ void bb_wbits(const float* wa, const float* wb, u64* Wbits) {
  int word = (blockIdx.x * blockDim.x + threadIdx.x) >> 6;
  int ln = threadIdx.x & 63;
  if (word >= 2 * OCH * NCH) return;
  const float* src = (word < OCH * NCH) ? wa : wb;
  int r = word % (OCH * NCH);          // r = oc*36 + ck over w[o][2304]
  u64 bits = __ballot(src[(size_t)r * 64 + ln] >= 0.f);
  int l = word / (OCH * NCH);
  int o = r / NCH, ck = r % NCH;
  if (ln == 0) Wbits[(size_t)l * OCH * NCH + (size_t)ck * OCH + o] = bits;
}

// stage 1b: i8 weight operand B'[layer][tap][oc][c] = sign(w[oc][c][tap]).
// Layout chosen so the MFMA B-fragment (lane=oc, bytes=16 consecutive c) is a
// single dwordx4 load.
__global__ void bb_wi8(const float* wa, const float* wb, signed char* B) {
  int tid = blockIdx.x * blockDim.x + threadIdx.x;   // 2*9*256*256 = 1179648
  if (tid >= 2 * 9 * 256 * 256) return;
  int c = tid & 255, o = (tid >> 8) & 255;
  int lt = tid >> 16, t = lt % 9, l = lt / 9;
  const float* src = l ? wb : wa;
  B[tid] = (src[((size_t)o * 256 + c) * 9 + t] >= 0.f) ? 1 : -1;
}

// stage 2: x0 sign bitplanes Sb[pixel][word] + i8 NHWC operand A[px][c].
__global__ void bb_xbits(const float* x, u64* Sb, signed char* A) {
  int wave = (blockIdx.x * blockDim.x + threadIdx.x) >> 6;
  int ln = threadIdx.x & 63;
  int h = wave & 31, wrd = (wave >> 5) & 3, n = wave >> 7;
  int c = wrd * 64 + ln;
  const float* row = x + ((size_t)((n * 256 + c) * 32 + h) << 5);
  signed char* arow = A + (((size_t)((n * 32 + h) * 32)) << 8) + c;
  #pragma unroll 4
  for (int w = 0; w < 32; ++w) {
    bool s = row[w] >= 0.f;
    u64 bits = __ballot(s);
    arow[(size_t)w << 8] = s ? 1 : -1;
    if (ln == 0) Sb[(size_t)((n * 32 + h) * 32 + w) * 4 + wrd] = bits;
  }
}

// stage 3: interior conv as i8 implicit GEMM on the matrix cores.
// Interior psums are even -> quantizer identity -> out = clip(full +/-1 dot).
// Wave computes a 32px x 32oc tile; K = 9 taps x 256 c via 72x
// mfma_i32_32x32x32_i8. px-tile = one (n,h) row (w = lane&31); taps are just
// +/-(32*dh+dw) pixel offsets in NHWC. h=0/31 rows and w=0/31 columns are
// boundary px, overwritten by bb_bconv (A has a 256B guard on each side so
// their garbage reads stay in-bounds). Any k-permutation inside the fragment
// cancels: A and B both use (lane>>5)*16+byte for the same c.
__global__ __launch_bounds__(256) void bb_gemm(const signed char* __restrict__ A,
                                               const signed char* __restrict__ B,
                                               short* __restrict__ dst) {
  int bx = blockIdx.x;                 // (n,h) row: px0 = bx*32
  int h = bx & 31;
  if (h == 0 || h == 31) return;       // whole row is boundary
  int wv = threadIdx.x >> 6, ln = threadIdx.x & 63;
  int oc0 = (blockIdx.y * 4 + wv) * 32;
  int px0 = bx * 32;
  int lw = ln & 31;                    // A row (= w) / B col (= oc) index
  int kh16 = (ln >> 5) * 16;           // k-half byte offset
  const signed char* arow = A + (((size_t)(px0 + lw)) << 8) + kh16;
  const signed char* brow = B + (((size_t)(oc0 + lw)) << 8) + kh16;
  i32x16 acc = {0, 0, 0, 0, 0, 0, 0, 0, 0, 0, 0, 0, 0, 0, 0, 0};
  for (int t = 0; t < 9; ++t) {
    int off = ((t / 3 - 1) * 32 + (t % 3 - 1)) << 8;   // tap shift in bytes
    const signed char* at = arow + off;
    const signed char* bt = brow + ((size_t)t << 16);
    #pragma unroll
    for (int j = 0; j < 8; ++j) {      // 8 c-blocks of 32
      i32x4 af = *(const i32x4*)(at + j * 32);
      i32x4 bf = *(const i32x4*)(bt + j * 32);
      acc = __builtin_amdgcn_mfma_i32_32x32x32_i8(af, bf, acc, 0, 0, 0);
    }
  }
  #pragma unroll
  for (int r = 0; r < 16; ++r) {       // C/D: col=lane&31, row=(r&3)+8*(r>>2)+4*(ln>>5)
    int m = (r & 3) + 8 * (r >> 2) + ((ln >> 5) << 2);
    int v = acc[r];
    v = v < -254 ? -254 : (v > 254 ? 254 : v);
    dst[(((size_t)(px0 + m)) << 8) + oc0 + lw] = (short)v;
  }
}

// stage 4: boundary pixels (124 per image, 3968 total), exact masked path.
// One block per px: threads 0..35 build the 36 patch words in LDS from Sb
// (spread-LUT, same math as the old bb_patch), then all 256 threads (= oc)
// do the masked XNOR-popcount with round-half-even per chunk.
__global__ __launch_bounds__(256) void bb_bconv(const u64* __restrict__ Sb,
                                                const u64* __restrict__ Wb,
                                                const u64* __restrict__ masks,
                                                short* __restrict__ dst) {
  __shared__ u64 spread[256];
  __shared__ u64 pw[NCH];
  __shared__ u64 mm[NCH];
  __shared__ int pm[NCH];
  int t = threadIdx.x;
  {
    u64 v = 0;
    for (int k = 0; k < 8; ++k) if (t & (1 << k)) v |= (u64)1 << (9 * k);
    spread[t] = v;
  }
  int b = blockIdx.x;
  int n = b / 124, r = b % 124;
  int h, w;
  if (r < 32)      { h = 0;      w = r;      }
  else if (r < 64) { h = 31;     w = r - 32; }
  else if (r < 94) { h = r - 63; w = 0;      }
  else             { h = r - 93; w = 31;     }
  int cls = (h == 0 ? 0 : (h == 31 ? 2 : 1)) * 3 + (w == 0 ? 0 : (w == 31 ? 2 : 1));
  __syncthreads();
  if (t < NCH) {
    int ck = t, base9 = ck % 9;
    u64 acc = 0;
    for (int tap = 0; tap < 9; ++tap) {
      int b0 = tap - base9; if (b0 < 0) b0 += 9;
      int nh = h + tap / 3 - 1, nw = w + tap % 3 - 1;
      if ((unsigned)nh <= 31u && (unsigned)nw <= 31u) {
        int run = (b0 == 0) ? 8 : 7;
        int c0 = (ck * 64 + b0) / 9;
        const u64* rp = Sb + ((size_t)((n * 32 + nh) * 32 + nw) << 2);
        int wi = c0 >> 6, sh = c0 & 63;
        u64 v = rp[wi] >> sh;
        if (sh + run > 64) v |= rp[wi + 1] << (64 - sh);
        v &= (run == 8) ? 0xFFull : 0x7Full;
        acc |= spread[(int)v] << b0;
      }
    }
    pw[ck] = acc;
    u64 m = masks[cls * NCH + ck];
    mm[ck] = m;
    pm[ck] = __popcll(m);
  }
  __syncthreads();
  int oc = t;
  int acc = 0;
  for (int i = 0; i < NCH; ++i) {
    int d = __popcll((pw[i] ^ Wb[(size_t)i * OCH + oc]) & mm[i]);
    int ps = pm[i] - 2 * d;
    acc += ps + (ps & 1) * ((ps & 2) - 1);
  }
  acc = acc < -254 ? -254 : (acc > 254 ? 254 : acc);
  int px = ((n * 32 + h) << 5) + w;
  dst[(size_t)px * OCH + oc] = (short)acc;
}

// stage 5: BN1 batch stats (integer values -> exact f32 sums).
__global__ void bb_stats1(const short* v16, float* st) {
  int t = threadIdx.x;
  const short* base = v16 + (size_t)blockIdx.x * 128 * OCH;
  int s = 0; float q = 0.f;
  for (int r = 0; r < 128; ++r) {
    int v = base[r * OCH + t];
    s += v; q += (float)(v * v);
  }
  atomicAdd(&st[t], (float)s);
  atomicAdd(&st[256 + t], q);
}

// stage 6: BN1 + hardtanh + sign-pack (hardtanh preserves sign) + i8 NHWC A2.
__global__ void bb_xbits2(const short* v16, const float* st,
                          const float* g, const float* b, u64* Sb,
                          signed char* A) {
  int wave = (blockIdx.x * blockDim.x + threadIdx.x) >> 6;
  int ln = threadIdx.x & 63;
  int wrd = wave & 3, px0 = (wave >> 2) * 32;
  int oc = wrd * 64 + ln;
  float mu = st[oc] * (1.f / 32768.f);
  float va = st[256 + oc] * (1.f / 32768.f) - mu * mu;
  float rs = rsqrtf(va + 1e-5f);
  float gg = g[oc], bb = b[oc];
  for (int j = 0; j < 32; ++j) {
    float bn = ((float)v16[(size_t)(px0 + j) * OCH + oc] - mu) * rs * gg + bb;
    bool s = bn >= 0.f;
    u64 bits = __ballot(s);
    A[(size_t)(px0 + j) * 256 + oc] = s ? 1 : -1;
    if (ln == 0) Sb[(size_t)(px0 + j) * 4 + wrd] = bits;
  }
}

// stage 7: BN2 batch stats of (conv2 + residual). Block = one (n,h) row-tile.
__global__ __launch_bounds__(256) void bb_stats2t(const short* __restrict__ pre16,
                                                  const float* __restrict__ x0,
                                                  float* st) {
  __shared__ float xt[32][257];
  int blk = blockIdx.x;                 // blk = n*32 + h
  int n = blk >> 5, h = blk & 31;
  int t = threadIdx.x;
  int w = t & 31, og = t >> 5;          // 8 oc-groups
  for (int k = 0; k < 32; ++k) {
    int oc = og * 32 + k;
    xt[w][oc] = x0[((size_t)(n * 256 + oc) * 32 + h) * 32 + w];
  }
  __syncthreads();
  int oc = t;
  size_t pb = (size_t)blk * 32 * OCH + oc;
  float s = 0.f, q = 0.f;
  for (int w2 = 0; w2 < 32; ++w2) {
    float v = (float)pre16[pb + (size_t)w2 * OCH] + xt[w2][oc];
    s += v; q += v * v;
  }
  atomicAdd(&st[512 + oc], s);
  atomicAdd(&st[768 + oc], q);
}

// stage 8: BN2 + hardtanh + NCHW store via in-place LDS transpose;
// reg output is data-independent: reg = reg0 + r1 + 2*r2 = reg0 + 8.625.
__global__ __launch_bounds__(256) void bb_fint(const short* __restrict__ pre16,
                                               const float* __restrict__ x0,
                                               const float* st, const float* g,
                                               const float* b, const float* r0,
                                               float* __restrict__ out) {
  __shared__ float xt[32][257];
  int blk = blockIdx.x;
  int n = blk >> 5, h = blk & 31;
  int t = threadIdx.x;
  int w = t & 31, og = t >> 5;
  for (int k = 0; k < 32; ++k) {
    int oc = og * 32 + k;
    xt[w][oc] = x0[((size_t)(n * 256 + oc) * 32 + h) * 32 + w];
  }
  __syncthreads();
  int oc = t;
  float mu = st[512 + oc] * (1.f / 32768.f);
  float va = st[768 + oc] * (1.f / 32768.f) - mu * mu;
  float rs = rsqrtf(va + 1e-5f);
  float gg = g[oc], bb = b[oc];
  size_t pb = (size_t)blk * 32 * OCH + oc;
  for (int w2 = 0; w2 < 32; ++w2) {
    float v = (float)pre16[pb + (size_t)w2 * OCH] + xt[w2][oc];
    v = (v - mu) * rs * gg + bb;
    xt[w2][oc] = fminf(fmaxf(v, -1.f), 1.f);   // in-place: col oc owned by thread
  }
  __syncthreads();
  for (int k = 0; k < 32; ++k) {
    int oc2 = og * 32 + k;
    out[((size_t)(n * 256 + oc2) * 32 + h) * 32 + w] = xt[w][oc2];
  }
  if (blk == 0 && t == 0) out[8388608] = r0[0] + 8.625f;
}

extern "C" void kernel_launch(void* const* d_in, const int* in_sizes, int n_in,
                              void* d_out, int out_size, void* d_ws, size_t ws_size,
                              hipStream_t stream) {
  const float* x0   = (const float*)d_in[0];
  const float* reg0 = (const float*)d_in[1];
  const float* w1   = (const float*)d_in[2];
  const float* g1   = (const float*)d_in[3];
  const float* b1   = (const float*)d_in[4];
  const float* w2   = (const float*)d_in[5];
  const float* g2   = (const float*)d_in[6];
  const float* b2   = (const float*)d_in[7];

  char* ws = (char*)d_ws;
  u64*   Wbits = (u64*)(ws);                        // 147456 B  [layer][ck][oc]
  u64*   masks = (u64*)(ws + 147456);               // 2592 B
  float* st    = (float*)(ws + 151552);             // 4 KiB
  u64*   Sb    = (u64*)(ws + 155648);               // 1 MiB
  signed char* Bi8 = (signed char*)(ws + 1204224);  // 1179648 B [l][t][o][c]
  signed char* Ai8 = (signed char*)(ws + 2383872) + 256;  // 8 MiB + 512B guard
  short* v16   = (short*)(ws + 10772992);           // 16777216 B (conv1 out,
                                                    //  then reused for conv2)

  bb_init   <<<1,    256, 0, stream>>>(st, masks);
  bb_wbits  <<<4608, 256, 0, stream>>>(w1, w2, Wbits);
  bb_wi8    <<<4608, 256, 0, stream>>>(w1, w2, Bi8);
  bb_xbits  <<<1024, 256, 0, stream>>>(x0, Sb, Ai8);
  bb_gemm   <<<dim3(1024, 2), 256, 0, stream>>>(Ai8, Bi8, v16);
  bb_bconv  <<<3968, 256, 0, stream>>>(Sb, Wbits, masks, v16);
  bb_stats1 <<<256,  256, 0, stream>>>(v16, st);
  bb_xbits2 <<<1024, 256, 0, stream>>>(v16, st, g1, b1, Sb, Ai8);
  bb_gemm   <<<dim3(1024, 2), 256, 0, stream>>>(Ai8, Bi8 + 9 * 256 * 256, v16);
  bb_bconv  <<<3968, 256, 0, stream>>>(Sb, Wbits + OCH * NCH, masks, v16);
  bb_stats2t<<<1024, 256, 0, stream>>>(v16, x0, st);
  bb_fint   <<<1024, 256, 0, stream>>>(v16, x0, st, g2, b2, reg0, (float*)d_out);
}

// Round 2
// 351.300 us; speedup vs baseline: 1.4747x; 1.4747x over previous
//
#include <hip/hip_runtime.h>

typedef unsigned long long u64;
typedef __attribute__((ext_vector_type(4)))  int i32x4;
typedef __attribute__((ext_vector_type(16))) int i32x16;

// x [32,256,32,32] f32, w [256,256,3,3] f32; reduction R = 2304 = 36 x 64.
#define NPIX   32768
#define OCH    256
#define NCH    36

// stage 0: zero stats; build the 9 boundary-class chunk masks.
__global__ void bb_init(float* st, u64* masks) {
  int t = threadIdx.x;
  for (int i = t; i < 1024; i += 256) st[i] = 0.f;
  for (int id = t; id < 9 * NCH; id += 256) {
    int cls = id / NCH, ck = id % NCH;
    int ch = cls / 3, cw = cls % 3;
    u64 m = 0;
    for (int b = 0; b < 64; ++b) {
      int r = ck * 64 + b, tap = r % 9, kh = tap / 3, kw = tap % 3;
      bool oob = (ch == 0 && kh == 0) || (ch == 2 && kh == 2) ||
                 (cw == 0 && kw == 0) || (cw == 2 && kw == 2);
      if (!oob) m |= (u64)1 << b;
    }
    masks[id] = m;
  }
}

// stage 1: weight sign bits, TRANSPOSED to WbitsT[layer][chunk][oc] so the
// boundary kernel's per-chunk weight reads coalesce (lanes = consecutive oc).
__global__ void bb_wbits(const float* wa, const float* wb, u64* Wbits) {
  int word = (blockIdx.x * blockDim.x + threadIdx.x) >> 6;
  int ln = threadIdx.x & 63;
  if (word >= 2 * OCH * NCH) return;
  const float* src = (word < OCH * NCH) ? wa : wb;
  int r = word % (OCH * NCH);          // r = oc*36 + ck over w[o][2304]
  u64 bits = __ballot(src[(size_t)r * 64 + ln] >= 0.f);
  int l = word / (OCH * NCH);
  int o = r / NCH, ck = r % NCH;
  if (ln == 0) Wbits[(size_t)l * OCH * NCH + (size_t)ck * OCH + o] = bits;
}

// stage 1b: i8 weight operand B'[layer][tap][oc][c] = sign(w[oc][c][tap]).
// Read-coalesced (tid = contiguous source index); the 1.2 MB of scattered
// sign-byte writes combine in L2.
__global__ void bb_wi8(const float* wa, const float* wb, signed char* B) {
  int tid = blockIdx.x * blockDim.x + threadIdx.x;   // 2 * 589824
  if (tid >= 2 * 589824) return;
  int l = tid >= 589824;
  int r = l ? tid - 589824 : tid;
  const float* src = l ? wb : wa;
  float v = src[r];
  int t = r % 9, oc9 = r / 9;
  int c = oc9 & 255, o = oc9 >> 8;
  B[(((size_t)(l * 9 + t) * 256 + o) << 8) + c] = (v >= 0.f) ? 1 : -1;
}

// stage 2: x0 sign bitplanes Sb[pixel][word] + i8 NHWC operand A[px][c].
// x0 is NCHW (c-major rows), so stage the (n,h) slice through a padded LDS
// transpose: global reads are w-contiguous (coalesced), ballots read LDS at
// bank (c+w)%32 (2-way = free).
__global__ __launch_bounds__(256) void bb_xbits(const float* __restrict__ x,
                                                u64* __restrict__ Sb,
                                                signed char* __restrict__ A) {
  __shared__ float xt[256][33];
  int n = blockIdx.x >> 5, h = blockIdx.x & 31;
  int t = threadIdx.x;
  int w = t & 31, cg = t >> 5;          // 8 c-groups
  for (int k = 0; k < 32; ++k) {
    int c = k * 8 + cg;
    xt[c][w] = x[((size_t)((n * 256 + c) * 32 + h) << 5) + w];
  }
  __syncthreads();
  int ln = t & 63, wv = t >> 6;         // 4 waves = 4 channel-words
  int c2 = wv * 64 + ln;
  for (int w2 = 0; w2 < 32; ++w2) {
    bool s = xt[c2][w2] >= 0.f;
    u64 bits = __ballot(s);
    int px = (n * 32 + h) * 32 + w2;
    A[(size_t)px * 256 + c2] = s ? 1 : -1;
    if (ln == 0) Sb[(size_t)px * 4 + wv] = bits;
  }
}

// stage 3: interior conv as i8 implicit GEMM on the matrix cores.
// Interior psums are even -> quantizer identity -> out = clip(full +/-1 dot).
// Wave computes 64px x 64oc (2x2 fragments of 32x32) so each K-step is
// 4 loads -> 4 MFMAs with 4 independent accumulator chains; block = 4 waves
// covering 64px x 256oc; grid = 512 blocks (2/CU). Boundary px compute
// garbage (A has 16 KiB guards so tap reads stay in-bounds) and are
// overwritten by bb_bconv. Any k-permutation inside the fragment cancels:
// A and B both use (lane>>5)*16+byte for the same c.
__global__ __launch_bounds__(256, 2) void bb_gemm(const signed char* __restrict__ A,
                                                  const signed char* __restrict__ B,
                                                  short* __restrict__ dst) {
  int wv = threadIdx.x >> 6, ln = threadIdx.x & 63;
  int lw = ln & 31;                    // A row (= px) / B col (= oc) index
  int kh16 = (ln >> 5) << 4;           // k-half byte offset
  int px0 = blockIdx.x << 6;           // 64-px tile = 2 (n,h) rows
  int oc0 = wv << 6;                   // 64-oc tile per wave
  const signed char* a0 = A + (((size_t)(px0 + lw)) << 8) + kh16;
  const signed char* a1 = a0 + (32 << 8);
  const signed char* b0 = B + (((size_t)(oc0 + lw)) << 8) + kh16;
  const signed char* b1 = b0 + (32 << 8);
  i32x16 acc00 = {0,0,0,0,0,0,0,0,0,0,0,0,0,0,0,0};
  i32x16 acc01 = acc00, acc10 = acc00, acc11 = acc00;
  for (int t = 0; t < 9; ++t) {
    int off = ((t / 3 - 1) * 32 + (t % 3 - 1)) << 8;   // tap shift in bytes
    const signed char* at0 = a0 + off;
    const signed char* at1 = a1 + off;
    const signed char* bt0 = b0 + ((size_t)t << 16);
    const signed char* bt1 = b1 + ((size_t)t << 16);
    #pragma unroll
    for (int j = 0; j < 8; ++j) {      // 8 c-blocks of 32
      i32x4 af0 = *(const i32x4*)(at0 + j * 32);
      i32x4 af1 = *(const i32x4*)(at1 + j * 32);
      i32x4 bf0 = *(const i32x4*)(bt0 + j * 32);
      i32x4 bf1 = *(const i32x4*)(bt1 + j * 32);
      acc00 = __builtin_amdgcn_mfma_i32_32x32x32_i8(af0, bf0, acc00, 0, 0, 0);
      acc01 = __builtin_amdgcn_mfma_i32_32x32x32_i8(af0, bf1, acc01, 0, 0, 0);
      acc10 = __builtin_amdgcn_mfma_i32_32x32x32_i8(af1, bf0, acc10, 0, 0, 0);
      acc11 = __builtin_amdgcn_mfma_i32_32x32x32_i8(af1, bf1, acc11, 0, 0, 0);
    }
  }
  int rbase = (ln >> 5) << 2;
  #pragma unroll
  for (int r = 0; r < 16; ++r) {       // C/D: col=lane&31, row=(r&3)+8*(r>>2)+4*(ln>>5)
    int m = (r & 3) + ((r >> 2) << 3) + rbase;
    size_t row0 = ((size_t)(px0 + m)) << 8;
    size_t row1 = ((size_t)(px0 + 32 + m)) << 8;
    int v;
    v = acc00[r]; v = v < -254 ? -254 : (v > 254 ? 254 : v);
    dst[row0 + oc0 + lw] = (short)v;
    v = acc01[r]; v = v < -254 ? -254 : (v > 254 ? 254 : v);
    dst[row0 + oc0 + 32 + lw] = (short)v;
    v = acc10[r]; v = v < -254 ? -254 : (v > 254 ? 254 : v);
    dst[row1 + oc0 + lw] = (short)v;
    v = acc11[r]; v = v < -254 ? -254 : (v > 254 ? 254 : v);
    dst[row1 + oc0 + 32 + lw] = (short)v;
  }
}

// stage 4: boundary pixels (124 per image, 3968 total), exact masked path.
// One block per px: threads 0..35 build the 36 patch words in LDS from Sb
// (spread-LUT, same math as the old bb_patch), then all 256 threads (= oc)
// do the masked XNOR-popcount with round-half-even per chunk.
__global__ __launch_bounds__(256) void bb_bconv(const u64* __restrict__ Sb,
                                                const u64* __restrict__ Wb,
                                                const u64* __restrict__ masks,
                                                short* __restrict__ dst) {
  __shared__ u64 spread[256];
  __shared__ u64 pw[NCH];
  __shared__ u64 mm[NCH];
  __shared__ int pm[NCH];
  int t = threadIdx.x;
  {
    u64 v = 0;
    for (int k = 0; k < 8; ++k) if (t & (1 << k)) v |= (u64)1 << (9 * k);
    spread[t] = v;
  }
  int b = blockIdx.x;
  int n = b / 124, r = b % 124;
  int h, w;
  if (r < 32)      { h = 0;      w = r;      }
  else if (r < 64) { h = 31;     w = r - 32; }
  else if (r < 94) { h = r - 63; w = 0;      }
  else             { h = r - 93; w = 31;     }
  int cls = (h == 0 ? 0 : (h == 31 ? 2 : 1)) * 3 + (w == 0 ? 0 : (w == 31 ? 2 : 1));
  __syncthreads();
  if (t < NCH) {
    int ck = t, base9 = ck % 9;
    u64 acc = 0;
    for (int tap = 0; tap < 9; ++tap) {
      int b0 = tap - base9; if (b0 < 0) b0 += 9;
      int nh = h + tap / 3 - 1, nw = w + tap % 3 - 1;
      if ((unsigned)nh <= 31u && (unsigned)nw <= 31u) {
        int run = (b0 == 0) ? 8 : 7;
        int c0 = (ck * 64 + b0) / 9;
        const u64* rp = Sb + ((size_t)((n * 32 + nh) * 32 + nw) << 2);
        int wi = c0 >> 6, sh = c0 & 63;
        u64 v = rp[wi] >> sh;
        if (sh + run > 64) v |= rp[wi + 1] << (64 - sh);
        v &= (run == 8) ? 0xFFull : 0x7Full;
        acc |= spread[(int)v] << b0;
      }
    }
    pw[ck] = acc;
    u64 m = masks[cls * NCH + ck];
    mm[ck] = m;
    pm[ck] = __popcll(m);
  }
  __syncthreads();
  int oc = t;
  int acc = 0;
  for (int i = 0; i < NCH; ++i) {
    int d = __popcll((pw[i] ^ Wb[(size_t)i * OCH + oc]) & mm[i]);
    int ps = pm[i] - 2 * d;
    acc += ps + (ps & 1) * ((ps & 2) - 1);
  }
  acc = acc < -254 ? -254 : (acc > 254 ? 254 : acc);
  int px = ((n * 32 + h) << 5) + w;
  dst[(size_t)px * OCH + oc] = (short)acc;
}

// stage 5: BN1 batch stats (integer values -> exact f32 sums).
__global__ void bb_stats1(const short* v16, float* st) {
  int t = threadIdx.x;
  const short* base = v16 + (size_t)blockIdx.x * 128 * OCH;
  int s = 0; float q = 0.f;
  for (int r = 0; r < 128; ++r) {
    int v = base[r * OCH + t];
    s += v; q += (float)(v * v);
  }
  atomicAdd(&st[t], (float)s);
  atomicAdd(&st[256 + t], q);
}

// stage 6: BN1 + hardtanh + sign-pack (hardtanh preserves sign) + i8 NHWC A2.
__global__ void bb_xbits2(const short* v16, const float* st,
                          const float* g, const float* b, u64* Sb,
                          signed char* A) {
  int wave = (blockIdx.x * blockDim.x + threadIdx.x) >> 6;
  int ln = threadIdx.x & 63;
  int wrd = wave & 3, px0 = (wave >> 2) * 32;
  int oc = wrd * 64 + ln;
  float mu = st[oc] * (1.f / 32768.f);
  float va = st[256 + oc] * (1.f / 32768.f) - mu * mu;
  float rs = rsqrtf(va + 1e-5f);
  float gg = g[oc], bb = b[oc];
  for (int j = 0; j < 32; ++j) {
    float bn = ((float)v16[(size_t)(px0 + j) * OCH + oc] - mu) * rs * gg + bb;
    bool s = bn >= 0.f;
    u64 bits = __ballot(s);
    A[(size_t)(px0 + j) * 256 + oc] = s ? 1 : -1;
    if (ln == 0) Sb[(size_t)(px0 + j) * 4 + wrd] = bits;
  }
}

// stage 7: BN2 batch stats of (conv2 + residual). Block = one (n,h) row-tile.
__global__ __launch_bounds__(256) void bb_stats2t(const short* __restrict__ pre16,
                                                  const float* __restrict__ x0,
                                                  float* st) {
  __shared__ float xt[32][257];
  int blk = blockIdx.x;                 // blk = n*32 + h
  int n = blk >> 5, h = blk & 31;
  int t = threadIdx.x;
  int w = t & 31, og = t >> 5;          // 8 oc-groups
  for (int k = 0; k < 32; ++k) {
    int oc = og * 32 + k;
    xt[w][oc] = x0[((size_t)(n * 256 + oc) * 32 + h) * 32 + w];
  }
  __syncthreads();
  int oc = t;
  size_t pb = (size_t)blk * 32 * OCH + oc;
  float s = 0.f, q = 0.f;
  for (int w2 = 0; w2 < 32; ++w2) {
    float v = (float)pre16[pb + (size_t)w2 * OCH] + xt[w2][oc];
    s += v; q += v * v;
  }
  atomicAdd(&st[512 + oc], s);
  atomicAdd(&st[768 + oc], q);
}

// stage 8: BN2 + hardtanh + NCHW store via in-place LDS transpose;
// reg output is data-independent: reg = reg0 + r1 + 2*r2 = reg0 + 8.625.
__global__ __launch_bounds__(256) void bb_fint(const short* __restrict__ pre16,
                                               const float* __restrict__ x0,
                                               const float* st, const float* g,
                                               const float* b, const float* r0,
                                               float* __restrict__ out) {
  __shared__ float xt[32][257];
  int blk = blockIdx.x;
  int n = blk >> 5, h = blk & 31;
  int t = threadIdx.x;
  int w = t & 31, og = t >> 5;
  for (int k = 0; k < 32; ++k) {
    int oc = og * 32 + k;
    xt[w][oc] = x0[((size_t)(n * 256 + oc) * 32 + h) * 32 + w];
  }
  __syncthreads();
  int oc = t;
  float mu = st[512 + oc] * (1.f / 32768.f);
  float va = st[768 + oc] * (1.f / 32768.f) - mu * mu;
  float rs = rsqrtf(va + 1e-5f);
  float gg = g[oc], bb = b[oc];
  size_t pb = (size_t)blk * 32 * OCH + oc;
  for (int w2 = 0; w2 < 32; ++w2) {
    float v = (float)pre16[pb + (size_t)w2 * OCH] + xt[w2][oc];
    v = (v - mu) * rs * gg + bb;
    xt[w2][oc] = fminf(fmaxf(v, -1.f), 1.f);   // in-place: col oc owned by thread
  }
  __syncthreads();
  for (int k = 0; k < 32; ++k) {
    int oc2 = og * 32 + k;
    out[((size_t)(n * 256 + oc2) * 32 + h) * 32 + w] = xt[w][oc2];
  }
  if (blk == 0 && t == 0) out[8388608] = r0[0] + 8.625f;
}

extern "C" void kernel_launch(void* const* d_in, const int* in_sizes, int n_in,
                              void* d_out, int out_size, void* d_ws, size_t ws_size,
                              hipStream_t stream) {
  const float* x0   = (const float*)d_in[0];
  const float* reg0 = (const float*)d_in[1];
  const float* w1   = (const float*)d_in[2];
  const float* g1   = (const float*)d_in[3];
  const float* b1   = (const float*)d_in[4];
  const float* w2   = (const float*)d_in[5];
  const float* g2   = (const float*)d_in[6];
  const float* b2   = (const float*)d_in[7];

  char* ws = (char*)d_ws;
  u64*   Wbits = (u64*)(ws);                        // 147456 B  [layer][ck][oc]
  u64*   masks = (u64*)(ws + 147456);               // 2592 B
  float* st    = (float*)(ws + 151552);             // 4 KiB
  u64*   Sb    = (u64*)(ws + 155648);               // 1 MiB
  signed char* Bi8 = (signed char*)(ws + 1204224);  // 1179648 B [l][t][o][c]
  signed char* Ai8 = (signed char*)(ws + 2383872) + 16384;  // 8 MiB + 16K guards
  short* v16   = (short*)(ws + 10805248);           // 16777216 B (conv1 out,
                                                    //  then reused for conv2)

  bb_init   <<<1,    256, 0, stream>>>(st, masks);
  bb_wbits  <<<4608, 256, 0, stream>>>(w1, w2, Wbits);
  bb_wi8    <<<4608, 256, 0, stream>>>(w1, w2, Bi8);
  bb_xbits  <<<1024, 256, 0, stream>>>(x0, Sb, Ai8);
  bb_gemm   <<<512,  256, 0, stream>>>(Ai8, Bi8, v16);
  bb_bconv  <<<3968, 256, 0, stream>>>(Sb, Wbits, masks, v16);
  bb_stats1 <<<256,  256, 0, stream>>>(v16, st);
  bb_xbits2 <<<1024, 256, 0, stream>>>(v16, st, g1, b1, Sb, Ai8);
  bb_gemm   <<<512,  256, 0, stream>>>(Ai8, Bi8 + 589824, v16);
  bb_bconv  <<<3968, 256, 0, stream>>>(Sb, Wbits + OCH * NCH, masks, v16);
  bb_stats2t<<<1024, 256, 0, stream>>>(v16, x0, st);
  bb_fint   <<<1024, 256, 0, stream>>>(v16, x0, st, g2, b2, reg0, (float*)d_out);
}

// Round 3
// 285.545 us; speedup vs baseline: 1.8143x; 1.2303x over previous
//
#include <hip/hip_runtime.h>

typedef unsigned long long u64;
typedef __attribute__((ext_vector_type(4)))  int i32x4;
typedef __attribute__((ext_vector_type(16))) int i32x16;

// x [32,256,32,32] f32, w [256,256,3,3] f32; reduction R = 2304 = 36 x 64.
#define NPIX   32768
#define OCH    256
#define NCH    36

// bb_gemm geometry: 128px x 128oc block, 4 waves of 64x64, BK=64, K=36 steps.
#define AROWS  196            // px tile 128 + tap halo (+-33)
#define ALDS   (AROWS * 256)  // 50176 B, staged ONCE per block (all taps, all K)
#define BLDS   8192           // 128 oc x 64 c, double-buffered
#define GLDS   (ALDS + 2 * BLDS)   // 66560 B dynamic LDS

__device__ __forceinline__ void gload16(const void* g, void* l) {
  __builtin_amdgcn_global_load_lds(
      (const __attribute__((address_space(1))) unsigned*)g,
      (__attribute__((address_space(3))) unsigned*)l, 16, 0, 0);
}

// stage 0: zero stats; build the 9 boundary-class chunk masks.
__global__ void bb_init(float* st, u64* masks) {
  int t = threadIdx.x;
  for (int i = t; i < 1024; i += 256) st[i] = 0.f;
  for (int id = t; id < 9 * NCH; id += 256) {
    int cls = id / NCH, ck = id % NCH;
    int ch = cls / 3, cw = cls % 3;
    u64 m = 0;
    for (int b = 0; b < 64; ++b) {
      int r = ck * 64 + b, tap = r % 9, kh = tap / 3, kw = tap % 3;
      bool oob = (ch == 0 && kh == 0) || (ch == 2 && kh == 2) ||
                 (cw == 0 && kw == 0) || (cw == 2 && kw == 2);
      if (!oob) m |= (u64)1 << b;
    }
    masks[id] = m;
  }
}

// stage 1: weight sign bits, TRANSPOSED to WbitsT[layer][chunk][oc] so the
// boundary kernel's per-chunk weight reads coalesce (lanes = consecutive oc).
__global__ void bb_wbits(const float* wa, const float* wb, u64* Wbits) {
  int word = (blockIdx.x * blockDim.x + threadIdx.x) >> 6;
  int ln = threadIdx.x & 63;
  if (word >= 2 * OCH * NCH) return;
  const float* src = (word < OCH * NCH) ? wa : wb;
  int r = word % (OCH * NCH);          // r = oc*36 + ck over w[o][2304]
  u64 bits = __ballot(src[(size_t)r * 64 + ln] >= 0.f);
  int l = word / (OCH * NCH);
  int o = r / NCH, ck = r % NCH;
  if (ln == 0) Wbits[(size_t)l * OCH * NCH + (size_t)ck * OCH + o] = bits;
}

// stage 1b: i8 weight operand B'[layer][tap][oc][c] = sign(w[oc][c][tap]).
__global__ void bb_wi8(const float* wa, const float* wb, signed char* B) {
  int tid = blockIdx.x * blockDim.x + threadIdx.x;   // 2 * 589824
  if (tid >= 2 * 589824) return;
  int l = tid >= 589824;
  int r = l ? tid - 589824 : tid;
  const float* src = l ? wb : wa;
  float v = src[r];
  int t = r % 9, oc9 = r / 9;
  int c = oc9 & 255, o = oc9 >> 8;
  B[(((size_t)(l * 9 + t) * 256 + o) << 8) + c] = (v >= 0.f) ? 1 : -1;
}

// stage 2: x0 sign bitplanes Sb[pixel][word] + i8 NHWC operand A[px][c].
// Staged through a padded LDS transpose so the NCHW reads coalesce.
__global__ __launch_bounds__(256) void bb_xbits(const float* __restrict__ x,
                                                u64* __restrict__ Sb,
                                                signed char* __restrict__ A) {
  __shared__ float xt[256][33];
  int n = blockIdx.x >> 5, h = blockIdx.x & 31;
  int t = threadIdx.x;
  int w = t & 31, cg = t >> 5;          // 8 c-groups
  for (int k = 0; k < 32; ++k) {
    int c = k * 8 + cg;
    xt[c][w] = x[((size_t)((n * 256 + c) * 32 + h) << 5) + w];
  }
  __syncthreads();
  int ln = t & 63, wv = t >> 6;         // 4 waves = 4 channel-words
  int c2 = wv * 64 + ln;
  for (int w2 = 0; w2 < 32; ++w2) {
    bool s = xt[c2][w2] >= 0.f;
    u64 bits = __ballot(s);
    int px = (n * 32 + h) * 32 + w2;
    A[(size_t)px * 256 + c2] = s ? 1 : -1;
    if (ln == 0) Sb[(size_t)px * 4 + wv] = bits;
  }
}

// stage 3: interior conv as LDS-staged i8 implicit GEMM (m97-style + T2 + T3).
// A slab [196 rows][256 c] staged once (covers all taps via +-33 row halo);
// B [128 oc][64 c] double-buffered per K-step. XOR-swizzled LDS (slot ^= row&7
// for A's 256B rows, row&3 for B's 64B rows), pre-swizzled on the global
// source so global_load_lds' linear-dest constraint is satisfied (rule 21).
// 2-phase loop: stage next-B -> compute -> vmcnt(0) -> raw barrier.
// Boundary px compute garbage (guards keep reads in-bounds), overwritten by
// bb_bconv. k-permutations inside fragments cancel (A,B share the mapping).
__global__ __launch_bounds__(256, 2) void bb_gemm(const signed char* __restrict__ A,
                                                  const signed char* __restrict__ B,
                                                  short* __restrict__ dst) {
  extern __shared__ signed char sm[];
  int t = threadIdx.x, wv = t >> 6, ln = t & 63;
  int lw = ln & 31, hk = ln >> 5;
  int px0 = blockIdx.x << 7;
  int oc0 = blockIdx.y << 7;

  // ---- stage A once: rows px0-33 .. px0+162 (196 rows x 256 B) ----
  const signed char* Abase = A + (size_t)(px0 - 33) * 256;
  #pragma unroll
  for (int i = 0; i < 13; ++i) {
    int c = i * 4 + wv;
    if (c < 49) {                        // 49 wave-calls x 1024 B = 50176 B
      int u = c * 64 + ln;
      int row = u >> 4, p = u & 15;
      gload16(Abase + (size_t)row * 256 + (((p ^ (row & 7)) << 4)),
              &sm[c * 1024]);
    }
  }

  // ---- B staging helper: K-step ks -> tap ks>>2, c-block ks&3 ----
  #define STAGE_B(bufi, ks) do {                                              \
    int tp_ = (ks) >> 2, cb_ = (ks) & 3;                                      \
    const signed char* Bb_ = B + ((size_t)tp_ << 16) + (size_t)oc0 * 256      \
                               + (cb_ << 6);                                  \
    _Pragma("unroll")                                                         \
    for (int i_ = 0; i_ < 2; ++i_) {                                          \
      int c_ = wv * 2 + i_;                                                   \
      int u_ = c_ * 64 + ln;                                                  \
      int row_ = u_ >> 2, p_ = u_ & 3;                                        \
      gload16(Bb_ + (size_t)row_ * 256 + (((p_ ^ (row_ & 3)) << 4)),          \
              &sm[ALDS + (bufi) * BLDS + c_ * 1024]);                         \
    }                                                                         \
  } while (0)

  STAGE_B(0, 0);
  asm volatile("s_waitcnt vmcnt(0)" ::: "memory");
  __builtin_amdgcn_s_barrier();

  int wm = wv >> 1, wn = wv & 1;
  int arow0 = 33 + (wm << 6) + lw;       // + dpx + mf*32 at use
  int brow0 = (wn << 6) + lw;            // + nf*32 at use
  i32x16 acc00 = {0,0,0,0,0,0,0,0,0,0,0,0,0,0,0,0};
  i32x16 acc01 = acc00, acc10 = acc00, acc11 = acc00;

  int buf = 0;
  for (int ks = 0; ks < 36; ++ks) {
    if (ks < 35) STAGE_B(buf ^ 1, ks + 1);
    int tp = ks >> 2, cb = ks & 3;
    int dpx = (tp / 3 - 1) * 32 + (tp % 3 - 1);
    int r0 = arow0 + dpx, r1 = r0 + 32;
    int q0 = brow0, q1 = brow0 + 32;
    const signed char* Bl = sm + ALDS + buf * BLDS;
    #pragma unroll
    for (int k32 = 0; k32 < 2; ++k32) {
      int sa = cb * 4 + k32 * 2 + hk;
      int sb = k32 * 2 + hk;
      i32x4 a0 = *(const i32x4*)(sm + r0 * 256 + ((sa ^ (r0 & 7)) << 4));
      i32x4 a1 = *(const i32x4*)(sm + r1 * 256 + ((sa ^ (r1 & 7)) << 4));
      i32x4 b0 = *(const i32x4*)(Bl + q0 * 64 + ((sb ^ (q0 & 3)) << 4));
      i32x4 b1 = *(const i32x4*)(Bl + q1 * 64 + ((sb ^ (q1 & 3)) << 4));
      acc00 = __builtin_amdgcn_mfma_i32_32x32x32_i8(a0, b0, acc00, 0, 0, 0);
      acc01 = __builtin_amdgcn_mfma_i32_32x32x32_i8(a0, b1, acc01, 0, 0, 0);
      acc10 = __builtin_amdgcn_mfma_i32_32x32x32_i8(a1, b0, acc10, 0, 0, 0);
      acc11 = __builtin_amdgcn_mfma_i32_32x32x32_i8(a1, b1, acc11, 0, 0, 0);
    }
    asm volatile("s_waitcnt vmcnt(0)" ::: "memory");
    __builtin_amdgcn_s_barrier();
    buf ^= 1;
  }
  #undef STAGE_B

  int px0w = px0 + (wm << 6), oc0w = oc0 + (wn << 6);
  int rbase = hk << 2;
  #pragma unroll
  for (int r = 0; r < 16; ++r) {       // C/D: col=lane&31, row=(r&3)+8*(r>>2)+4*hk
    int m = (r & 3) + ((r >> 2) << 3) + rbase;
    size_t row0 = ((size_t)(px0w + m)) << 8;
    size_t row1 = ((size_t)(px0w + 32 + m)) << 8;
    int v;
    v = acc00[r]; v = v < -254 ? -254 : (v > 254 ? 254 : v);
    dst[row0 + oc0w + lw] = (short)v;
    v = acc01[r]; v = v < -254 ? -254 : (v > 254 ? 254 : v);
    dst[row0 + oc0w + 32 + lw] = (short)v;
    v = acc10[r]; v = v < -254 ? -254 : (v > 254 ? 254 : v);
    dst[row1 + oc0w + lw] = (short)v;
    v = acc11[r]; v = v < -254 ? -254 : (v > 254 ? 254 : v);
    dst[row1 + oc0w + 32 + lw] = (short)v;
  }
}

// stage 4: boundary pixels (124 per image, 3968 total), exact masked path.
__global__ __launch_bounds__(256) void bb_bconv(const u64* __restrict__ Sb,
                                                const u64* __restrict__ Wb,
                                                const u64* __restrict__ masks,
                                                short* __restrict__ dst) {
  __shared__ u64 spread[256];
  __shared__ u64 pw[NCH];
  __shared__ u64 mm[NCH];
  __shared__ int pm[NCH];
  int t = threadIdx.x;
  {
    u64 v = 0;
    for (int k = 0; k < 8; ++k) if (t & (1 << k)) v |= (u64)1 << (9 * k);
    spread[t] = v;
  }
  int b = blockIdx.x;
  int n = b / 124, r = b % 124;
  int h, w;
  if (r < 32)      { h = 0;      w = r;      }
  else if (r < 64) { h = 31;     w = r - 32; }
  else if (r < 94) { h = r - 63; w = 0;      }
  else             { h = r - 93; w = 31;     }
  int cls = (h == 0 ? 0 : (h == 31 ? 2 : 1)) * 3 + (w == 0 ? 0 : (w == 31 ? 2 : 1));
  __syncthreads();
  if (t < NCH) {
    int ck = t, base9 = ck % 9;
    u64 acc = 0;
    for (int tap = 0; tap < 9; ++tap) {
      int b0 = tap - base9; if (b0 < 0) b0 += 9;
      int nh = h + tap / 3 - 1, nw = w + tap % 3 - 1;
      if ((unsigned)nh <= 31u && (unsigned)nw <= 31u) {
        int run = (b0 == 0) ? 8 : 7;
        int c0 = (ck * 64 + b0) / 9;
        const u64* rp = Sb + ((size_t)((n * 32 + nh) * 32 + nw) << 2);
        int wi = c0 >> 6, sh = c0 & 63;
        u64 v = rp[wi] >> sh;
        if (sh + run > 64) v |= rp[wi + 1] << (64 - sh);
        v &= (run == 8) ? 0xFFull : 0x7Full;
        acc |= spread[(int)v] << b0;
      }
    }
    pw[ck] = acc;
    u64 m = masks[cls * NCH + ck];
    mm[ck] = m;
    pm[ck] = __popcll(m);
  }
  __syncthreads();
  int oc = t;
  int acc = 0;
  for (int i = 0; i < NCH; ++i) {
    int d = __popcll((pw[i] ^ Wb[(size_t)i * OCH + oc]) & mm[i]);
    int ps = pm[i] - 2 * d;
    acc += ps + (ps & 1) * ((ps & 2) - 1);
  }
  acc = acc < -254 ? -254 : (acc > 254 ? 254 : acc);
  int px = ((n * 32 + h) << 5) + w;
  dst[(size_t)px * OCH + oc] = (short)acc;
}

// stage 5: BN1 batch stats (integer values -> exact f32 sums).
__global__ void bb_stats1(const short* v16, float* st) {
  int t = threadIdx.x;
  const short* base = v16 + (size_t)blockIdx.x * 128 * OCH;
  int s = 0; float q = 0.f;
  for (int r = 0; r < 128; ++r) {
    int v = base[r * OCH + t];
    s += v; q += (float)(v * v);
  }
  atomicAdd(&st[t], (float)s);
  atomicAdd(&st[256 + t], q);
}

// stage 6: BN1 + hardtanh + sign-pack (hardtanh preserves sign) + i8 NHWC A2.
__global__ void bb_xbits2(const short* v16, const float* st,
                          const float* g, const float* b, u64* Sb,
                          signed char* A) {
  int wave = (blockIdx.x * blockDim.x + threadIdx.x) >> 6;
  int ln = threadIdx.x & 63;
  int wrd = wave & 3, px0 = (wave >> 2) * 32;
  int oc = wrd * 64 + ln;
  float mu = st[oc] * (1.f / 32768.f);
  float va = st[256 + oc] * (1.f / 32768.f) - mu * mu;
  float rs = rsqrtf(va + 1e-5f);
  float gg = g[oc], bb = b[oc];
  for (int j = 0; j < 32; ++j) {
    float bn = ((float)v16[(size_t)(px0 + j) * OCH + oc] - mu) * rs * gg + bb;
    bool s = bn >= 0.f;
    u64 bits = __ballot(s);
    A[(size_t)(px0 + j) * 256 + oc] = s ? 1 : -1;
    if (ln == 0) Sb[(size_t)(px0 + j) * 4 + wrd] = bits;
  }
}

// stage 7: BN2 batch stats of (conv2 + residual). Block = one (n,h) row-tile.
__global__ __launch_bounds__(256) void bb_stats2t(const short* __restrict__ pre16,
                                                  const float* __restrict__ x0,
                                                  float* st) {
  __shared__ float xt[32][257];
  int blk = blockIdx.x;                 // blk = n*32 + h
  int n = blk >> 5, h = blk & 31;
  int t = threadIdx.x;
  int w = t & 31, og = t >> 5;          // 8 oc-groups
  for (int k = 0; k < 32; ++k) {
    int oc = og * 32 + k;
    xt[w][oc] = x0[((size_t)(n * 256 + oc) * 32 + h) * 32 + w];
  }
  __syncthreads();
  int oc = t;
  size_t pb = (size_t)blk * 32 * OCH + oc;
  float s = 0.f, q = 0.f;
  for (int w2 = 0; w2 < 32; ++w2) {
    float v = (float)pre16[pb + (size_t)w2 * OCH] + xt[w2][oc];
    s += v; q += v * v;
  }
  atomicAdd(&st[512 + oc], s);
  atomicAdd(&st[768 + oc], q);
}

// stage 8: BN2 + hardtanh + NCHW store via in-place LDS transpose;
// reg output is data-independent: reg = reg0 + r1 + 2*r2 = reg0 + 8.625.
__global__ __launch_bounds__(256) void bb_fint(const short* __restrict__ pre16,
                                               const float* __restrict__ x0,
                                               const float* st, const float* g,
                                               const float* b, const float* r0,
                                               float* __restrict__ out) {
  __shared__ float xt[32][257];
  int blk = blockIdx.x;
  int n = blk >> 5, h = blk & 31;
  int t = threadIdx.x;
  int w = t & 31, og = t >> 5;
  for (int k = 0; k < 32; ++k) {
    int oc = og * 32 + k;
    xt[w][oc] = x0[((size_t)(n * 256 + oc) * 32 + h) * 32 + w];
  }
  __syncthreads();
  int oc = t;
  float mu = st[512 + oc] * (1.f / 32768.f);
  float va = st[768 + oc] * (1.f / 32768.f) - mu * mu;
  float rs = rsqrtf(va + 1e-5f);
  float gg = g[oc], bb = b[oc];
  size_t pb = (size_t)blk * 32 * OCH + oc;
  for (int w2 = 0; w2 < 32; ++w2) {
    float v = (float)pre16[pb + (size_t)w2 * OCH] + xt[w2][oc];
    v = (v - mu) * rs * gg + bb;
    xt[w2][oc] = fminf(fmaxf(v, -1.f), 1.f);   // in-place: col oc owned by thread
  }
  __syncthreads();
  for (int k = 0; k < 32; ++k) {
    int oc2 = og * 32 + k;
    out[((size_t)(n * 256 + oc2) * 32 + h) * 32 + w] = xt[w][oc2];
  }
  if (blk == 0 && t == 0) out[8388608] = r0[0] + 8.625f;
}

extern "C" void kernel_launch(void* const* d_in, const int* in_sizes, int n_in,
                              void* d_out, int out_size, void* d_ws, size_t ws_size,
                              hipStream_t stream) {
  const float* x0   = (const float*)d_in[0];
  const float* reg0 = (const float*)d_in[1];
  const float* w1   = (const float*)d_in[2];
  const float* g1   = (const float*)d_in[3];
  const float* b1   = (const float*)d_in[4];
  const float* w2   = (const float*)d_in[5];
  const float* g2   = (const float*)d_in[6];
  const float* b2   = (const float*)d_in[7];

  char* ws = (char*)d_ws;
  u64*   Wbits = (u64*)(ws);                        // 147456 B  [layer][ck][oc]
  u64*   masks = (u64*)(ws + 147456);               // 2592 B
  float* st    = (float*)(ws + 151552);             // 4 KiB
  u64*   Sb    = (u64*)(ws + 155648);               // 1 MiB
  signed char* Bi8 = (signed char*)(ws + 1204224);  // 1179648 B [l][t][o][c]
  signed char* Ai8 = (signed char*)(ws + 2383872) + 32768;  // 8 MiB + 32K guards
  short* v16   = (short*)(ws + 10838016);           // 16 MiB (conv1 out,
                                                    //  then reused for conv2)

  bb_init   <<<1,    256, 0, stream>>>(st, masks);
  bb_wbits  <<<4608, 256, 0, stream>>>(w1, w2, Wbits);
  bb_wi8    <<<4608, 256, 0, stream>>>(w1, w2, Bi8);
  bb_xbits  <<<1024, 256, 0, stream>>>(x0, Sb, Ai8);
  bb_gemm   <<<dim3(256, 2), 256, GLDS, stream>>>(Ai8, Bi8, v16);
  bb_bconv  <<<3968, 256, 0, stream>>>(Sb, Wbits, masks, v16);
  bb_stats1 <<<256,  256, 0, stream>>>(v16, st);
  bb_xbits2 <<<1024, 256, 0, stream>>>(v16, st, g1, b1, Sb, Ai8);
  bb_gemm   <<<dim3(256, 2), 256, GLDS, stream>>>(Ai8, Bi8 + 589824, v16);
  bb_bconv  <<<3968, 256, 0, stream>>>(Sb, Wbits + OCH * NCH, masks, v16);
  bb_stats2t<<<1024, 256, 0, stream>>>(v16, x0, st);
  bb_fint   <<<1024, 256, 0, stream>>>(v16, x0, st, g2, b2, reg0, (float*)d_out);
}